// Round 1
// baseline (3997.196 us; speedup 1.0000x reference)
//
#include <hip/hip_runtime.h>
#include <hip/hip_bf16.h>
#include <stdint.h>

#define VOCAB 10000
#define HID   256
#define BATCH 32
#define STEPS 256

__device__ __forceinline__ float bf2f(unsigned short u) {
    union { unsigned int ui; float f; } v;
    v.ui = ((unsigned int)u) << 16;
    return v.f;
}

__device__ __forceinline__ unsigned short f2bf(float f) {
    union { float f; unsigned int ui; } v;
    v.f = f;
    unsigned int u = v.ui;
    // round-to-nearest-even
    unsigned int r = (u + 0x7FFFu + ((u >> 16) & 1u)) >> 16;
    return (unsigned short)r;
}

// ---------------------------------------------------------------------------
// Prep: convert the three 256x256 hidden-weight matrices to bf16 in d_ws.
// Layout in ws: [Wz | Wr | Wh], each 65536 ushorts.
// ---------------------------------------------------------------------------
__global__ void prep_bf16(const float* __restrict__ Wz,
                          const float* __restrict__ Wr,
                          const float* __restrict__ Wh,
                          unsigned short* __restrict__ out) {
    int i = blockIdx.x * 256 + threadIdx.x;
    if (i < HID * HID) {
        out[i]                 = f2bf(Wz[i]);
        out[HID * HID + i]     = f2bf(Wr[i]);
        out[2 * HID * HID + i] = f2bf(Wh[i]);
    }
}

// ---------------------------------------------------------------------------
// Recurrence: one block per batch row (32 blocks x 256 threads).
// Thread j owns hidden column j. h state in LDS; weights streamed (bf16, L2).
// Writes h_t for every step to h_hist (layout [t][b][j] == output row t*32+b)
// and the final h to h_final.
// ---------------------------------------------------------------------------
__global__ __launch_bounds__(HID) void gru_rec(
    const int*   __restrict__ X,      // [BATCH][STEPS]
    const float* __restrict__ H0,     // [BATCH][HID]
    const float* __restrict__ Wxz, const float* __restrict__ Wxr,
    const float* __restrict__ Wxh,    // [VOCAB][HID]
    const float* __restrict__ bz, const float* __restrict__ br,
    const float* __restrict__ bh,     // [HID]
    const unsigned short* __restrict__ Wbf,  // [3][HID][HID] bf16
    float* __restrict__ h_hist,       // [STEPS][BATCH][HID]
    float* __restrict__ h_final)      // [BATCH][HID]
{
    const int b = blockIdx.x;
    const int j = threadIdx.x;

    __shared__ float hs[HID];
    __shared__ float rhs[HID];

    const unsigned short* Wz = Wbf;
    const unsigned short* Wr = Wbf + HID * HID;
    const unsigned short* Wh = Wbf + 2 * HID * HID;

    hs[j] = H0[b * HID + j];
    const float bzj = bz[j], brj = br[j], bhj = bh[j];
    __syncthreads();

    for (int t = 0; t < STEPS; ++t) {
        const int x = X[b * STEPS + t];

        float sz = Wxz[(size_t)x * HID + j] + bzj;
        float sr = Wxr[(size_t)x * HID + j] + brj;
        #pragma unroll 8
        for (int k = 0; k < HID; ++k) {
            float hk = hs[k];  // LDS broadcast (all lanes same k)
            sz += hk * bf2f(Wz[k * HID + j]);
            sr += hk * bf2f(Wr[k * HID + j]);
        }
        float z = 1.0f / (1.0f + __expf(-sz));
        float r = 1.0f / (1.0f + __expf(-sr));
        float hj = hs[j];
        rhs[j] = r * hj;
        __syncthreads();  // rhs ready; also: everyone done reading hs

        float sh = Wxh[(size_t)x * HID + j] + bhj;
        #pragma unroll 8
        for (int k = 0; k < HID; ++k) {
            sh += rhs[k] * bf2f(Wh[k * HID + j]);
        }
        float ht = tanhf(sh);
        float hn = z * hj + (1.0f - z) * ht;

        hs[j] = hn;  // safe: hs reads all happened before the barrier above
        h_hist[((size_t)t * BATCH + b) * HID + j] = hn;
        __syncthreads();  // hs[j] visible before next step's dot products
    }
    h_final[b * HID + j] = hs[j];
}

// ---------------------------------------------------------------------------
// Projection: C[8192][10000] = A[8192][256] @ B[256][10000] + bq
// f32 LDS-tiled GEMM, BM=BN=64, BK=16, 256 threads, 4x4 per thread.
// ---------------------------------------------------------------------------
#define BM 64
#define BN 64
#define BK 16

__global__ __launch_bounds__(256) void proj_gemm(
    const float* __restrict__ A,   // [8192][HID]
    const float* __restrict__ B,   // [HID][VOCAB]
    const float* __restrict__ bq,  // [VOCAB]
    float* __restrict__ C)         // [8192][VOCAB]
{
    __shared__ float As[BK][BM];  // A tile, transposed (k-major)
    __shared__ float Bs[BK][BN];

    const int tid = threadIdx.x;
    const int m0 = blockIdx.y * BM;
    const int n0 = blockIdx.x * BN;
    const int tx = tid & 15;   // n direction
    const int ty = tid >> 4;   // m direction

    // A tile load mapping: 64 rows x 16 k = 1024 floats; float4 along k.
    const int a_row = tid >> 2;        // 0..63
    const int a_kq  = (tid & 3) * 4;   // 0,4,8,12
    // B tile load mapping: 16 k-rows x 64 n; float4 along n.
    const int b_row = tid >> 4;        // 0..15
    const int b_col = (tid & 15) * 4;  // 0..60

    float acc[4][4] = {};

    for (int k0 = 0; k0 < HID; k0 += BK) {
        float4 av = *(const float4*)(A + (size_t)(m0 + a_row) * HID + k0 + a_kq);
        As[a_kq + 0][a_row] = av.x;
        As[a_kq + 1][a_row] = av.y;
        As[a_kq + 2][a_row] = av.z;
        As[a_kq + 3][a_row] = av.w;

        int bn = n0 + b_col;
        float4 bv = make_float4(0.f, 0.f, 0.f, 0.f);
        if (bn + 3 < VOCAB) {
            bv = *(const float4*)(B + (size_t)(k0 + b_row) * VOCAB + bn);
        } else {
            float tmp[4] = {0.f, 0.f, 0.f, 0.f};
            #pragma unroll
            for (int q = 0; q < 4; ++q)
                if (bn + q < VOCAB) tmp[q] = B[(size_t)(k0 + b_row) * VOCAB + bn + q];
            bv = make_float4(tmp[0], tmp[1], tmp[2], tmp[3]);
        }
        *(float4*)&Bs[b_row][b_col] = bv;
        __syncthreads();

        #pragma unroll
        for (int k = 0; k < BK; ++k) {
            float a4[4], b4[4];
            #pragma unroll
            for (int i = 0; i < 4; ++i) a4[i] = As[k][ty * 4 + i];
            #pragma unroll
            for (int i = 0; i < 4; ++i) b4[i] = Bs[k][tx * 4 + i];
            #pragma unroll
            for (int i = 0; i < 4; ++i)
                #pragma unroll
                for (int q = 0; q < 4; ++q)
                    acc[i][q] += a4[i] * b4[q];
        }
        __syncthreads();
    }

    #pragma unroll
    for (int i = 0; i < 4; ++i) {
        int m = m0 + ty * 4 + i;
        int n = n0 + tx * 4;
        if (n + 3 < VOCAB) {
            float4 cv = make_float4(acc[i][0] + bq[n + 0],
                                    acc[i][1] + bq[n + 1],
                                    acc[i][2] + bq[n + 2],
                                    acc[i][3] + bq[n + 3]);
            *(float4*)(C + (size_t)m * VOCAB + n) = cv;
        } else {
            #pragma unroll
            for (int q = 0; q < 4; ++q)
                if (n + q < VOCAB)
                    C[(size_t)m * VOCAB + n + q] = acc[i][q] + bq[n + q];
        }
    }
}

// ---------------------------------------------------------------------------
extern "C" void kernel_launch(void* const* d_in, const int* in_sizes, int n_in,
                              void* d_out, int out_size, void* d_ws, size_t ws_size,
                              hipStream_t stream) {
    const int*   X   = (const int*)  d_in[0];
    const float* H0  = (const float*)d_in[1];
    const float* Wxz = (const float*)d_in[2];
    const float* Whz = (const float*)d_in[3];
    const float* bz  = (const float*)d_in[4];
    const float* Wxr = (const float*)d_in[5];
    const float* Whr = (const float*)d_in[6];
    const float* br  = (const float*)d_in[7];
    const float* Wxh = (const float*)d_in[8];
    const float* Whh = (const float*)d_in[9];
    const float* bh  = (const float*)d_in[10];
    const float* Whq = (const float*)d_in[11];
    const float* bq  = (const float*)d_in[12];

    float* out     = (float*)d_out;
    float* h_final = out + (size_t)STEPS * BATCH * VOCAB;  // second tuple output

    unsigned short* wbf = (unsigned short*)d_ws;
    float* h_hist = (float*)((char*)d_ws + 3 * HID * HID * sizeof(unsigned short));

    // 1) weights -> bf16 (65536 elems per matrix, 256 blocks x 256 thr)
    prep_bf16<<<256, 256, 0, stream>>>(Whz, Whr, Whh, wbf);

    // 2) sequential recurrence, one block per batch row
    gru_rec<<<BATCH, HID, 0, stream>>>(X, H0, Wxz, Wxr, Wxh, bz, br, bh,
                                       wbf, h_hist, h_final);

    // 3) batched output projection
    dim3 grid((VOCAB + BN - 1) / BN, (STEPS * BATCH) / BM);
    proj_gemm<<<grid, 256, 0, stream>>>(h_hist, Whq, bq, out);
}

// Round 2
// 1395.926 us; speedup vs baseline: 2.8635x; 2.8635x over previous
//
#include <hip/hip_runtime.h>
#include <hip/hip_bf16.h>
#include <stdint.h>

#define VOCAB 10000
#define HID   256
#define BATCH 32
#define STEPS 256

typedef __attribute__((ext_vector_type(8))) short short8;
typedef __attribute__((ext_vector_type(4))) float floatx4;

__device__ __forceinline__ float bf2f(unsigned short u) {
    union { unsigned int ui; float f; } v;
    v.ui = ((unsigned int)u) << 16;
    return v.f;
}

__device__ __forceinline__ unsigned short f2bf(float f) {
    union { float f; unsigned int ui; } v;
    v.f = f;
    unsigned int u = v.ui;
    unsigned int r = (u + 0x7FFFu + ((u >> 16) & 1u)) >> 16;  // RNE
    return (unsigned short)r;
}

// packed bf16x2 dot product: acc += lo(w)*lo(h) + hi(w)*hi(h)
#if __has_builtin(__builtin_amdgcn_fdot2_f32_bf16)
typedef __bf16 bf16x2 __attribute__((ext_vector_type(2)));
__device__ __forceinline__ float dot2(unsigned int w, unsigned int h, float acc) {
    union { unsigned int u; bf16x2 v; } a, b;
    a.u = w; b.u = h;
    return __builtin_amdgcn_fdot2_f32_bf16(a.v, b.v, acc, false);
}
#else
__device__ __forceinline__ float dot2(unsigned int w, unsigned int h, float acc) {
    union { unsigned int u; float f; } w0, w1, h0, h1;
    w0.u = w << 16; w1.u = w & 0xFFFF0000u;
    h0.u = h << 16; h1.u = h & 0xFFFF0000u;
    acc = fmaf(w0.f, h0.f, acc);
    acc = fmaf(w1.f, h1.f, acc);
    return acc;
}
#endif

__device__ __forceinline__ float sigmoidf_(float x) {
    return __builtin_amdgcn_rcpf(1.0f + __expf(-x));
}
__device__ __forceinline__ float tanhf_(float x) {
    // 1 - 2/(exp(2x)+1); correct limits at +-inf with v_exp
    float e = __expf(2.0f * x);
    return 1.0f - 2.0f * __builtin_amdgcn_rcpf(e + 1.0f);
}

// ---------------------------------------------------------------------------
// prep_w: Whz/Whr/Whh f32[256][256] -> Wsw[g][p4(32)][j(256)][m(8)] bf16
//   Wsw entry (g,p4,j,m) = W_g[p4*8+m][j]   (k-pairs contiguous per column j)
// grid (3, 256), 256 thr. Reads coalesced.
// ---------------------------------------------------------------------------
__global__ void prep_w(const float* __restrict__ Wz, const float* __restrict__ Wr,
                       const float* __restrict__ Wh, unsigned short* __restrict__ out) {
    int g = blockIdx.x, k = blockIdx.y, j = threadIdx.x;
    const float* W = (g == 0) ? Wz : (g == 1) ? Wr : Wh;
    float v = W[k * HID + j];
    int p4 = k >> 3, m = k & 7;
    out[(((size_t)g * 32 + p4) * HID + j) * 8 + m] = f2bf(v);
}

// ---------------------------------------------------------------------------
// prep_b: Whq f32[256][10000] -> B-fragment buffer for mfma_16x16x32_bf16
//   bfr[nt(625)][kc(8)][lane(64)][jj(8)] = Whq[kc*32 + (lane>>4)*8 + jj][nt*16 + (lane&15)]
// grid (40, 256), 256 thr. Reads coalesced, writes scattered (one-time).
// ---------------------------------------------------------------------------
__global__ void prep_b(const float* __restrict__ Whq, unsigned short* __restrict__ bfr) {
    int k = blockIdx.y;
    int n = blockIdx.x * 256 + threadIdx.x;
    if (n >= VOCAB) return;
    float v = Whq[(size_t)k * VOCAB + n];
    int nt = n >> 4, l15 = n & 15;
    int kc = k >> 5, kr = k & 31;
    int quad = kr >> 3, jj = kr & 7;
    int lane = quad * 16 + l15;
    bfr[(((size_t)nt * 8 + kc) * 64 + lane) * 8 + jj] = f2bf(v);
}

// ---------------------------------------------------------------------------
// gru_rec: 32 blocks (one batch row) x 512 threads (8 waves).
//   Threads 0..255  (group A, col j): z-gate full-K dot, then h-gate K-low half,
//                                     activations/blend, owns the f32 h chain.
//   Threads 256..511 (group B, col j): r-gate full-K dot, rh, h-gate K-high half.
// Weights: bf16 pre-swizzled (Wsw), streamed from L2 as dwordx4 (4 bf16-pairs).
// h state: bf16 in LDS (broadcast b128 reads feed dot2 pairs).
// x one-hot projections: rows gathered into LDS, double-buffered, prefetched.
// ---------------------------------------------------------------------------
__global__ __launch_bounds__(512) void gru_rec(
    const int* __restrict__ X, const float* __restrict__ H0,
    const float* __restrict__ Wxz, const float* __restrict__ Wxr,
    const float* __restrict__ Wxh,
    const float* __restrict__ bz, const float* __restrict__ br,
    const float* __restrict__ bh,
    const unsigned short* __restrict__ Wsw,
    unsigned short* __restrict__ hist,   // [STEPS*BATCH][HID] bf16
    float* __restrict__ h_final)         // [BATCH][HID] f32
{
    const int b = blockIdx.x;
    const int tid = threadIdx.x;
    const bool isA = tid < HID;
    const int j = isA ? tid : tid - HID;

    __shared__ __align__(16) unsigned short hbuf[HID];
    __shared__ __align__(16) unsigned short rhbuf[HID];
    __shared__ float part[HID];
    __shared__ float xrow[2][3][HID];
    __shared__ int Xl[STEPS];

    const uint4* wA = (const uint4*)Wsw + (size_t)(isA ? 0 : 1) * 32 * HID + j; // z or r
    const uint4* wH = (const uint4*)Wsw + (size_t)2 * 32 * HID + j;             // h

    float h_my = H0[b * HID + j];
    float bias = isA ? bz[j] : br[j];
    float bhj  = isA ? bh[j] : 0.0f;

    if (isA) { hbuf[j] = f2bf(h_my); Xl[j] = X[b * STEPS + j]; }
    __syncthreads();

    {   // initial x-row gather for t=0
        int x0 = Xl[0];
        if (isA) {
            xrow[0][0][j] = Wxz[(size_t)x0 * HID + j];
            xrow[0][2][j] = Wxh[(size_t)x0 * HID + j];
        } else {
            xrow[0][1][j] = Wxr[(size_t)x0 * HID + j];
        }
    }
    __syncthreads();

    float z = 0.0f;

    for (int t = 0; t < STEPS; ++t) {
        const int cur = t & 1, nxt = cur ^ 1;

        // prefetch next step's x-projection rows (wraps harmlessly at t=255)
        const int xn = Xl[(t + 1) & (STEPS - 1)];
        float p0 = 0.f, p1 = 0.f;
        if (isA) {
            p0 = Wxz[(size_t)xn * HID + j];
            p1 = Wxh[(size_t)xn * HID + j];
        } else {
            p0 = Wxr[(size_t)xn * HID + j];
        }

        // z-gate (A) / r-gate (B): full-K dot over h pairs
        float acc = 0.0f;
        {
            const uint4* hp = (const uint4*)hbuf;
            #pragma unroll 8
            for (int i = 0; i < 32; ++i) {
                uint4 wv = wA[i * HID];
                uint4 hv = hp[i];
                acc = dot2(wv.x, hv.x, acc);
                acc = dot2(wv.y, hv.y, acc);
                acc = dot2(wv.z, hv.z, acc);
                acc = dot2(wv.w, hv.w, acc);
            }
        }

        if (isA) {
            z = sigmoidf_(acc + xrow[cur][0][j] + bias);
            xrow[nxt][0][j] = p0;
            xrow[nxt][2][j] = p1;
        } else {
            float r = sigmoidf_(acc + xrow[cur][1][j] + bias);
            rhbuf[j] = f2bf(r * h_my);
            xrow[nxt][1][j] = p0;
        }
        __syncthreads();  // B1: rhbuf + xrow[nxt] published

        // h-gate: K split between groups (A: pairs 0..63, B: 64..127)
        float acch = 0.0f;
        {
            const uint4* rp = (const uint4*)rhbuf;
            const int i0 = isA ? 0 : 16;
            #pragma unroll 8
            for (int i = 0; i < 16; ++i) {
                uint4 wv = wH[(i0 + i) * HID];
                uint4 hv = rp[i0 + i];
                acch = dot2(wv.x, hv.x, acch);
                acch = dot2(wv.y, hv.y, acch);
                acch = dot2(wv.z, hv.z, acch);
                acch = dot2(wv.w, hv.w, acch);
            }
        }
        if (!isA) part[j] = acch;
        __syncthreads();  // B2: h-gate partials published

        if (isA) {
            float hpre = acch + part[j] + xrow[cur][2][j] + bhj;
            float ht = tanhf_(hpre);
            float hn = z * h_my + (1.0f - z) * ht;
            h_my = hn;
            unsigned short hb = f2bf(hn);
            hbuf[j] = hb;
            hist[((size_t)t * BATCH + b) * HID + j] = hb;
        }
        __syncthreads();  // B3: hbuf published

        if (!isA) h_my = bf2f(hbuf[j]);  // B's h copy (bf16-rounded, used only for rh)
    }

    if (isA) h_final[b * HID + j] = h_my;
}

// ---------------------------------------------------------------------------
// proj: C[8192][10000] = A[8192][256](bf16) @ B[256][10000](bf16) + bq, f32 out
// MFMA 16x16x32, no LDS. Block: 256 thr (4 waves), BM=128 (8 m-tiles),
// 4 n-tiles per wave (block covers 16 n-tiles). B from pre-swizzled frag buf
// (coalesced dwordx4); A straight from bf16 h_hist (16B/lane, 64B/quad-col).
// ---------------------------------------------------------------------------
__global__ __launch_bounds__(256, 2) void proj(
    const unsigned short* __restrict__ Abf,  // h_hist [8192][256] bf16
    const unsigned short* __restrict__ Bfr,  // frag buffer [625][8][64][8]
    const float* __restrict__ bq,
    float* __restrict__ C)
{
    const int tid  = threadIdx.x;
    const int wave = tid >> 6;
    const int lane = tid & 63;
    const int l15  = lane & 15;
    const int quad = lane >> 4;

    const int nb = blockIdx.x;   // 0..39
    const int mb = blockIdx.y;   // 0..63
    const int m0 = mb * 128;
    const int nt0 = nb * 16 + wave * 4;

    floatx4 acc[8][4];
    #pragma unroll
    for (int i = 0; i < 8; ++i)
        #pragma unroll
        for (int q = 0; q < 4; ++q)
            acc[i][q] = (floatx4)0.0f;

    // clamp n-tiles for loads in the ragged tail block (stores are guarded)
    int ntc[4];
    #pragma unroll
    for (int q = 0; q < 4; ++q) {
        int nt = nt0 + q;
        ntc[q] = (nt < 625) ? nt : 624;
    }

    for (int kc = 0; kc < 8; ++kc) {
        short8 a[8];
        #pragma unroll
        for (int mt = 0; mt < 8; ++mt) {
            const unsigned short* ap =
                Abf + (size_t)(m0 + mt * 16 + l15) * HID + kc * 32 + quad * 8;
            a[mt] = *(const short8*)ap;
        }
        short8 bfrg[4];
        #pragma unroll
        for (int q = 0; q < 4; ++q) {
            const unsigned short* bp =
                Bfr + ((((size_t)ntc[q] * 8 + kc) * 64) + lane) * 8;
            bfrg[q] = *(const short8*)bp;
        }
        #pragma unroll
        for (int mt = 0; mt < 8; ++mt)
            #pragma unroll
            for (int q = 0; q < 4; ++q)
                acc[mt][q] = __builtin_amdgcn_mfma_f32_16x16x32_bf16(
                    a[mt], bfrg[q], acc[mt][q], 0, 0, 0);
    }

    // epilogue: bias + store (C/D layout: col = lane&15, row = quad*4 + reg)
    #pragma unroll
    for (int q = 0; q < 4; ++q) {
        int nt = nt0 + q;
        if (nt >= 625) continue;
        int col = nt * 16 + l15;
        float bqv = bq[col];
        #pragma unroll
        for (int mt = 0; mt < 8; ++mt) {
            int rowb = m0 + mt * 16 + quad * 4;
            #pragma unroll
            for (int r = 0; r < 4; ++r) {
                C[(size_t)(rowb + r) * VOCAB + col] = acc[mt][q][r] + bqv;
            }
        }
    }
}

// ---------------------------------------------------------------------------
extern "C" void kernel_launch(void* const* d_in, const int* in_sizes, int n_in,
                              void* d_out, int out_size, void* d_ws, size_t ws_size,
                              hipStream_t stream) {
    const int*   X   = (const int*)  d_in[0];
    const float* H0  = (const float*)d_in[1];
    const float* Wxz = (const float*)d_in[2];
    const float* Whz = (const float*)d_in[3];
    const float* bz  = (const float*)d_in[4];
    const float* Wxr = (const float*)d_in[5];
    const float* Whr = (const float*)d_in[6];
    const float* br  = (const float*)d_in[7];
    const float* Wxh = (const float*)d_in[8];
    const float* Whh = (const float*)d_in[9];
    const float* bh  = (const float*)d_in[10];
    const float* Whq = (const float*)d_in[11];
    const float* bq  = (const float*)d_in[12];

    float* out     = (float*)d_out;
    float* h_final = out + (size_t)STEPS * BATCH * VOCAB;

    // ws layout (ushorts): Wsw[196608] | Bfr[2560000] | hist[2097152]  = 9.26 MB
    unsigned short* wsw  = (unsigned short*)d_ws;
    unsigned short* bfr  = wsw + 196608;
    unsigned short* hist = bfr + 2560000;

    prep_w<<<dim3(3, 256), 256, 0, stream>>>(Whz, Whr, Whh, wsw);
    prep_b<<<dim3(40, 256), 256, 0, stream>>>(Whq, bfr);
    gru_rec<<<BATCH, 512, 0, stream>>>(X, H0, Wxz, Wxr, Wxh, bz, br, bh,
                                       wsw, hist, h_final);
    proj<<<dim3(40, 64), 256, 0, stream>>>(hist, bfr, bq, out);
}